// Round 3
// baseline (832.526 us; speedup 1.0000x reference)
//
#include <hip/hip_runtime.h>
#include <math.h>

#define BM 128
#define BN 128
#define BK 32

typedef _Float16 f16x8 __attribute__((ext_vector_type(8)));
typedef __attribute__((ext_vector_type(4))) float f32x4;

typedef const __attribute__((address_space(1))) void* gas_ptr;
typedef __attribute__((address_space(3))) void* las_ptr;

enum { OP_NONE = 0, OP_BIAS_GELU = 1, OP_BIAS = 2, OP_SCALE_MASK = 3 };

__device__ __forceinline__ unsigned short f2h(float f) {
    _Float16 h = (_Float16)f;  // RTNE
    unsigned short u;
    __builtin_memcpy(&u, &h, 2);
    return u;
}
__device__ __forceinline__ float h2f(unsigned short u) {
    _Float16 h;
    __builtin_memcpy(&h, &u, 2);
    return (float)h;
}

// C = A @ B with B given transposed (BT is [N][K] row-major). A [M][K], C
// [M][N]. fp16 in, fp32 accumulate, fp16 or fp32 out. lda==K, ldb==K, ldc==N.
// bias fp32. EPI: epilogue op. CAUSAL_K: limit K to bm+BM (scores@v).
template <int EPI, bool CAUSAL_K, bool F32OUT>
__global__ __launch_bounds__(256) void gemm_bt(
    const unsigned short* __restrict__ A,
    const unsigned short* __restrict__ BT,
    void* __restrict__ Cw,
    const float* __restrict__ bias,
    int M, int N, int K,
    long long sA, long long sB, long long sC,
    float scale)
{
    __shared__ __align__(16) unsigned short As[BM * BK];
    __shared__ __align__(16) unsigned short Bs[BN * BK];

    const int tid  = threadIdx.x;
    const int wave = tid >> 6;
    const int lane = tid & 63;

    const int bm = blockIdx.y * BM;
    const int bn = blockIdx.x * BN;

    const unsigned short* Ab = A  + (long long)blockIdx.z * sA;
    const unsigned short* Bb = BT + (long long)blockIdx.z * sB;
    unsigned short* Cb16 = (unsigned short*)Cw + (long long)blockIdx.z * sC;
    float*          Cb32 = (float*)Cw          + (long long)blockIdx.z * sC;

    const int wm = (wave >> 1) * 64;  // wave's 64x64 quadrant
    const int wn = (wave & 1) * 64;

    const int er = lane >> 4;   // quad (C/D row group)
    const int ec = lane & 15;   // C/D col

    // scores fast path: tile entirely above the diagonal -> all zeros
    if (EPI == OP_SCALE_MASK && bn >= bm + BM) {
        #pragma unroll
        for (int i = 0; i < 4; i++)
            #pragma unroll
            for (int j = 0; j < 4; j++)
                #pragma unroll
                for (int r = 0; r < 4; r++) {
                    int row = bm + wm + i * 16 + er * 4 + r;
                    int col = bn + wn + j * 16 + ec;
                    Cb16[(long long)row * N + col] = 0;
                }
        return;
    }

    f32x4 acc[4][4];
    #pragma unroll
    for (int i = 0; i < 4; i++)
        #pragma unroll
        for (int j = 0; j < 4; j++)
            acc[i][j] = (f32x4){0.f, 0.f, 0.f, 0.f};

    // staging: lane l -> LDS offset base + l*16B exactly (global_load_lds
    // wave-uniform-base requirement, m104/m108)
    const int sr = lane >> 2;
    const int sk = (lane & 3) * 8;

    int Keff = K;
    if (CAUSAL_K) {
        int kl = bm + BM;
        Keff = kl < K ? kl : K;
    }

    for (int k0 = 0; k0 < Keff; k0 += BK) {
        #pragma unroll
        for (int t = 0; t < 2; ++t) {
            int ra = wave * 32 + t * 16 + sr;  // 0..127 across block
            const unsigned short* gA = Ab + (long long)(bm + ra) * K + (k0 + sk);
            __builtin_amdgcn_global_load_lds((gas_ptr)(const void*)gA,
                                             (las_ptr)(void*)&As[ra * BK + sk],
                                             16, 0, 0);
            const unsigned short* gB = Bb + (long long)(bn + ra) * K + (k0 + sk);
            __builtin_amdgcn_global_load_lds((gas_ptr)(const void*)gB,
                                             (las_ptr)(void*)&Bs[ra * BK + sk],
                                             16, 0, 0);
        }
        __syncthreads();  // drains vmcnt -> staged data visible

        const int fr = lane & 15;        // A: m row / B: n col
        const int fk = (lane >> 4) * 8;  // k-offset within BK=32
        f16x8 fa[4], fb[4];
        #pragma unroll
        for (int i = 0; i < 4; i++)
            fa[i] = *(const f16x8*)&As[(wm + i * 16 + fr) * BK + fk];
        #pragma unroll
        for (int j = 0; j < 4; j++)
            fb[j] = *(const f16x8*)&Bs[(wn + j * 16 + fr) * BK + fk];
        #pragma unroll
        for (int i = 0; i < 4; i++)
            #pragma unroll
            for (int j = 0; j < 4; j++)
                acc[i][j] = __builtin_amdgcn_mfma_f32_16x16x32_f16(
                    fa[i], fb[j], acc[i][j], 0, 0, 0);
        __syncthreads();  // protect LDS before next stage overwrites
    }

    // epilogue: C/D layout col=lane&15, row=(lane>>4)*4+reg  [m89/m91]
    #pragma unroll
    for (int j = 0; j < 4; j++) {
        int col = bn + wn + j * 16 + ec;
        float bj = 0.f;
        if (EPI == OP_BIAS || EPI == OP_BIAS_GELU) bj = bias[col];
        #pragma unroll
        for (int i = 0; i < 4; i++) {
            #pragma unroll
            for (int r = 0; r < 4; r++) {
                int row = bm + wm + i * 16 + er * 4 + r;
                float v = acc[i][j][r];
                if (EPI == OP_BIAS_GELU) {
                    v += bj;
                    v = 0.5f * v * (1.f + erff(v * 0.70710678118654752f));
                } else if (EPI == OP_BIAS) {
                    v += bj;
                } else if (EPI == OP_SCALE_MASK) {
                    v *= scale;
                    if (col > row) v = 0.f;
                }
                if (F32OUT)
                    Cb32[(long long)row * N + col] = v;
                else
                    Cb16[(long long)row * N + col] = f2h(v);
            }
        }
    }
}

// fp32 -> fp16 elementwise (n divisible by 1024)
__global__ __launch_bounds__(256) void cvt_f32_f16(
    const float4* __restrict__ in, ushort4* __restrict__ out)
{
    int i = blockIdx.x * 256 + threadIdx.x;
    float4 f = in[i];
    ushort4 o;
    o.x = f2h(f.x); o.y = f2h(f.y); o.z = f2h(f.z); o.w = f2h(f.w);
    out[i] = o;
}

// out[col][row] = fp16(in[row][col]); in fp32 [rows][cols]
__global__ __launch_bounds__(256) void transpose_f32_f16(
    const float* __restrict__ in, unsigned short* __restrict__ out,
    int rows, int cols)
{
    __shared__ unsigned short tile[32][33];
    const int bx = blockIdx.x * 32;  // col base
    const int by = blockIdx.y * 32;  // row base
    const int x = threadIdx.x;
    for (int y = threadIdx.y; y < 32; y += 8)
        tile[y][x] = f2h(in[(long long)(by + y) * cols + (bx + x)]);
    __syncthreads();
    for (int y = threadIdx.y; y < 32; y += 8)
        out[(long long)(bx + y) * rows + (by + x)] = tile[x][y];
}

// fp16 transpose, batched via z
__global__ __launch_bounds__(256) void transpose_f16(
    const unsigned short* __restrict__ in,
    unsigned short* __restrict__ out,
    int rows, int cols,
    long long sIn, long long sOut)
{
    __shared__ unsigned short tile[32][33];
    const unsigned short* ip = in  + (long long)blockIdx.z * sIn;
    unsigned short*       op = out + (long long)blockIdx.z * sOut;
    const int bx = blockIdx.x * 32;
    const int by = blockIdx.y * 32;
    const int x = threadIdx.x;
    for (int y = threadIdx.y; y < 32; y += 8)
        tile[y][x] = ip[(long long)(by + y) * cols + (bx + x)];
    __syncthreads();
    for (int y = threadIdx.y; y < 32; y += 8)
        op[(long long)(bx + y) * rows + (by + x)] = tile[x][y];
}

// one 256-thread block per row of 1024; fp32 in, fp32 params, fp32 out
__global__ __launch_bounds__(256) void layernorm_f32(
    const float* __restrict__ X,
    const float* __restrict__ W,
    const float* __restrict__ Bv,
    float* __restrict__ Y)
{
    const int row = blockIdx.x;
    const int tid = threadIdx.x;
    float4 f = ((const float4*)(X + (long long)row * 1024))[tid];
    float s  = f.x + f.y + f.z + f.w;
    float ss = f.x * f.x + f.y * f.y + f.z * f.z + f.w * f.w;
    #pragma unroll
    for (int off = 32; off > 0; off >>= 1) {
        s  += __shfl_down(s, off);
        ss += __shfl_down(ss, off);
    }
    __shared__ float red[2][4];
    const int wv = tid >> 6;
    if ((tid & 63) == 0) { red[0][wv] = s; red[1][wv] = ss; }
    __syncthreads();
    float S  = red[0][0] + red[0][1] + red[0][2] + red[0][3];
    float SS = red[1][0] + red[1][1] + red[1][2] + red[1][3];
    float mu  = S * (1.f / 1024.f);
    float var = SS * (1.f / 1024.f) - mu * mu;
    float rs  = rsqrtf(var + 1e-5f);
    float4 w4 = ((const float4*)W)[tid];
    float4 b4 = ((const float4*)Bv)[tid];
    float4 o;
    o.x = (f.x - mu) * rs * w4.x + b4.x;
    o.y = (f.y - mu) * rs * w4.y + b4.y;
    o.z = (f.z - mu) * rs * w4.z + b4.z;
    o.w = (f.w - mu) * rs * w4.w + b4.w;
    ((float4*)(Y + (long long)row * 1024))[tid] = o;
}

extern "C" void kernel_launch(void* const* d_in, const int* in_sizes, int n_in,
                              void* d_out, int out_size, void* d_ws, size_t ws_size,
                              hipStream_t stream)
{
    const int C  = 1024;
    const int T  = 2048;
    const int NB = 8;
    const int MT = NB * T;  // 16384 rows

    const float* x = (const float*)d_in[0];
    const float* W1[3] = {(const float*)d_in[1], (const float*)d_in[5],
                          (const float*)d_in[9]};
    const float* b1[3] = {(const float*)d_in[2], (const float*)d_in[6],
                          (const float*)d_in[10]};
    const float* W2[3] = {(const float*)d_in[3], (const float*)d_in[7],
                          (const float*)d_in[11]};
    const float* b2[3] = {(const float*)d_in[4], (const float*)d_in[8],
                          (const float*)d_in[12]};
    const float* lnw = (const float*)d_in[13];
    const float* lnb = (const float*)d_in[14];

    char* wsp = (char*)d_ws;
    auto take = [&](size_t bytes) {
        char* p = wsp;
        wsp += (bytes + 255) & ~(size_t)255;
        return p;
    };

    const size_t MAT = (size_t)MT * C * 2;  // 33.55 MB f16 [16384][1024]

    unsigned short* W1T[3];
    unsigned short* W2T[3];
    for (int hh = 0; hh < 3; hh++) {
        W1T[hh] = (unsigned short*)take((size_t)C * C * 2);
        W2T[hh] = (unsigned short*)take((size_t)C * C * 2);
    }
    unsigned short* xb   = (unsigned short*)take(MAT);
    unsigned short* hbuf = (unsigned short*)take(MAT);
    unsigned short* qb   = (unsigned short*)take(MAT);  // contiguous after hbuf
    unsigned short* kb   = (unsigned short*)take(MAT);
    unsigned short* vb   = (unsigned short*)take((size_t)NB * T * T * 2);
    unsigned short* vT   = xb;            // xb dead after the MLPs
    unsigned short* scb  = vb;            // vb dead after its transpose into vT
    float*          opre = (float*)hbuf;  // spans hbuf+qb (both dead), 67.1 MB

    // x: fp32 -> fp16
    cvt_f32_f16<<<dim3(MT * C / 1024, 1, 1), dim3(256, 1, 1), 0, stream>>>(
        (const float4*)x, (ushort4*)xb);

    // weights: fp32 -> fp16 transposed ([out][in] for gemm_bt's BT operand)
    dim3 tb(32, 8, 1);
    dim3 gw(C / 32, C / 32, 1);
    for (int hh = 0; hh < 3; hh++) {
        transpose_f32_f16<<<gw, tb, 0, stream>>>(W1[hh], W1T[hh], C, C);
        transpose_f32_f16<<<gw, tb, 0, stream>>>(W2[hh], W2T[hh], C, C);
    }

    dim3 blk(256, 1, 1);
    dim3 gMLP(C / BN, MT / BM, 1);
    unsigned short* qkv[3] = {qb, kb, vb};
    for (int hh = 0; hh < 3; hh++) {
        gemm_bt<OP_BIAS_GELU, false, false><<<gMLP, blk, 0, stream>>>(
            xb, W1T[hh], hbuf, b1[hh], MT, C, C, 0, 0, 0, 1.f);
        gemm_bt<OP_BIAS, false, false><<<gMLP, blk, 0, stream>>>(
            hbuf, W2T[hh], qkv[hh], b2[hh], MT, C, C, 0, 0, 0, 1.f);
    }

    // vT[b] = v[b]^T ([C][T] per batch) for the scores@v GEMM's BT operand
    transpose_f16<<<dim3(C / 32, T / 32, NB), tb, 0, stream>>>(
        vb, vT, T, C, (long long)T * C, (long long)T * C);

    // scores = tril(q @ k^T) / sqrt(C*T); k already in BT ([T][C]) layout
    float inv_scale = 1.0f / sqrtf((float)C * (float)T);
    gemm_bt<OP_SCALE_MASK, false, false><<<dim3(T / BN, T / BM, NB), blk, 0, stream>>>(
        qb, kb, scb, nullptr, T, T, C,
        (long long)T * C, (long long)T * C, (long long)T * T, inv_scale);

    // out_pre = scores @ v (K limited to bm+BM by causality), fp32 out
    gemm_bt<OP_NONE, true, true><<<dim3(C / BN, T / BM, NB), blk, 0, stream>>>(
        scb, vT, opre, nullptr, T, C, T,
        (long long)T * T, (long long)T * C, (long long)T * C, 1.f);

    layernorm_f32<<<dim3(MT, 1, 1), dim3(256, 1, 1), 0, stream>>>(
        opre, lnw, lnb, (float*)d_out);
}

// Round 4
// 668.065 us; speedup vs baseline: 1.2462x; 1.2462x over previous
//
#include <hip/hip_runtime.h>
#include <math.h>

#define BM 128
#define BN 128
#define BK 64

typedef _Float16 f16x8 __attribute__((ext_vector_type(8)));
typedef __attribute__((ext_vector_type(4))) float f32x4;

typedef const __attribute__((address_space(1))) void* gas_ptr;
typedef __attribute__((address_space(3))) void* las_ptr;

enum { OP_NONE = 0, OP_BIAS_GELU = 1, OP_BIAS = 2, OP_SCALE_MASK = 3 };

__device__ __forceinline__ unsigned short f2h(float f) {
    _Float16 h = (_Float16)f;  // RTNE
    unsigned short u;
    __builtin_memcpy(&u, &h, 2);
    return u;
}
__device__ __forceinline__ float h2f(unsigned short u) {
    _Float16 h;
    __builtin_memcpy(&h, &u, 2);
    return (float)h;
}

// C = A @ B, B given transposed (BT is [N][K] row-major). A [M][K], C [M][N].
// fp16 in/out, fp32 accumulate. BK=64 with XOR-swizzled LDS staging:
//   stage: lane l of slab t fetches global chunk ((l&7)^((l>>3)&7)) of row
//          t*8+(l>>3)  -> LDS slot t*64+l  (slot = 16B unit)
//   read:  fragment (row r, chunk c) at slot r*8 + (c ^ (r&7))
// This keeps global_load_lds's forced contiguous LDS mapping AND spreads
// ds_read_b128 over all 8 bank groups (linear 128B-stride layout would be a
// 16-way conflict). z-batched: blockIdx.z strides A/B/C and selects bias.
template <int EPI, bool CAUSAL_K>
__global__ __launch_bounds__(256) void gemm_bt(
    const unsigned short* __restrict__ A,
    const unsigned short* __restrict__ BT,
    unsigned short* __restrict__ Cw,
    const float* __restrict__ bias0,
    const float* __restrict__ bias1,
    const float* __restrict__ bias2,
    int M, int N, int K,
    long long sA, long long sB, long long sC,
    float scale)
{
    __shared__ __align__(16) unsigned short As[BM * BK];
    __shared__ __align__(16) unsigned short Bs[BN * BK];

    const int tid  = threadIdx.x;
    const int wave = tid >> 6;
    const int lane = tid & 63;

    const int bm = blockIdx.y * BM;
    const int bn = blockIdx.x * BN;
    const int z  = blockIdx.z;

    // scores tiles fully above the diagonal are never read downstream
    if (EPI == OP_SCALE_MASK && bn >= bm + BM) return;

    const unsigned short* Ab = A  + (long long)z * sA;
    const unsigned short* Bb = BT + (long long)z * sB;
    unsigned short*       Cb = Cw + (long long)z * sC;
    const float* bias = nullptr;
    if (EPI == OP_BIAS || EPI == OP_BIAS_GELU)
        bias = (z == 0) ? bias0 : (z == 1) ? bias1 : bias2;

    const int wm = (wave >> 1) * 64;  // wave's 64x64 quadrant
    const int wn = (wave & 1) * 64;

    f32x4 acc[4][4];
    #pragma unroll
    for (int i = 0; i < 4; i++)
        #pragma unroll
        for (int j = 0; j < 4; j++)
            acc[i][j] = (f32x4){0.f, 0.f, 0.f, 0.f};

    int Keff = K;
    if (CAUSAL_K) {
        int kl = bm + BM;
        Keff = kl < K ? kl : K;
    }

    const int srow = lane >> 3;                          // row within 8-row slab
    const int gchw = ((lane & 7) ^ (srow & 7)) * 8;      // swizzled chunk, halfwords
    const int fr   = lane & 15;
    const int quad = lane >> 4;

    for (int k0 = 0; k0 < Keff; k0 += BK) {
        #pragma unroll
        for (int s = 0; s < 4; ++s) {
            const int t   = wave * 4 + s;
            const int row = t * 8 + srow;
            const unsigned short* gA = Ab + (long long)(bm + row) * K + (k0 + gchw);
            __builtin_amdgcn_global_load_lds((gas_ptr)(const void*)gA,
                                             (las_ptr)(void*)&As[t * 512 + lane * 8],
                                             16, 0, 0);
            const unsigned short* gB = Bb + (long long)(bn + row) * K + (k0 + gchw);
            __builtin_amdgcn_global_load_lds((gas_ptr)(const void*)gB,
                                             (las_ptr)(void*)&Bs[t * 512 + lane * 8],
                                             16, 0, 0);
        }
        __syncthreads();  // drains vmcnt -> staged data visible

        #pragma unroll
        for (int kk = 0; kk < 2; ++kk) {
            f16x8 fa[4], fb[4];
            #pragma unroll
            for (int i = 0; i < 4; i++) {
                const int row  = wm + i * 16 + fr;
                const int slot = row * 8 + ((kk * 4 + quad) ^ (fr & 7));
                fa[i] = *(const f16x8*)&As[slot * 8];
            }
            #pragma unroll
            for (int j = 0; j < 4; j++) {
                const int row  = wn + j * 16 + fr;
                const int slot = row * 8 + ((kk * 4 + quad) ^ (fr & 7));
                fb[j] = *(const f16x8*)&Bs[slot * 8];
            }
            #pragma unroll
            for (int i = 0; i < 4; i++)
                #pragma unroll
                for (int j = 0; j < 4; j++)
                    acc[i][j] = __builtin_amdgcn_mfma_f32_16x16x32_f16(
                        fa[i], fb[j], acc[i][j], 0, 0, 0);
        }
        __syncthreads();  // protect LDS before next stage overwrites
    }

    // epilogue: C/D layout col=lane&15, row=(lane>>4)*4+reg  [m89/m91]
    const int er = quad;
    const int ec = fr;
    #pragma unroll
    for (int j = 0; j < 4; j++) {
        const int col = bn + wn + j * 16 + ec;
        float bj = 0.f;
        if (EPI == OP_BIAS || EPI == OP_BIAS_GELU) bj = bias[col];
        #pragma unroll
        for (int i = 0; i < 4; i++) {
            #pragma unroll
            for (int r = 0; r < 4; r++) {
                const int row = bm + wm + i * 16 + er * 4 + r;
                float v = acc[i][j][r];
                if (EPI == OP_BIAS_GELU) {
                    v += bj;
                    v = 0.5f * v * (1.f + erff(v * 0.70710678118654752f));
                } else if (EPI == OP_BIAS) {
                    v += bj;
                } else if (EPI == OP_SCALE_MASK) {
                    v *= scale;
                    if (col > row) v = 0.f;
                }
                Cb[(long long)row * N + col] = f2h(v);
            }
        }
    }
}

// fp32 -> fp16 elementwise (n divisible by 1024)
__global__ __launch_bounds__(256) void cvt_f32_f16(
    const float4* __restrict__ in, ushort4* __restrict__ out)
{
    int i = blockIdx.x * 256 + threadIdx.x;
    float4 f = in[i];
    ushort4 o;
    o.x = f2h(f.x); o.y = f2h(f.y); o.z = f2h(f.z); o.w = f2h(f.w);
    out[i] = o;
}

// all six weight matrices: fp32 -> fp16 transposed, one dispatch (z=0..5).
// z 0..2 -> W1{q,k,v} into W1T+z*C*C ; z 3..5 -> W2{q,k,v} into W2T+(z-3)*C*C
__global__ __launch_bounds__(256) void wprep(
    const float* __restrict__ s0, const float* __restrict__ s1,
    const float* __restrict__ s2, const float* __restrict__ s3,
    const float* __restrict__ s4, const float* __restrict__ s5,
    unsigned short* __restrict__ W1T, unsigned short* __restrict__ W2T)
{
    const int C = 1024;
    const int z = blockIdx.z;
    const float* in = (z == 0) ? s0 : (z == 1) ? s1 : (z == 2) ? s2
                    : (z == 3) ? s3 : (z == 4) ? s4 : s5;
    unsigned short* out = (z < 3) ? (W1T + (long long)z * C * C)
                                  : (W2T + (long long)(z - 3) * C * C);
    __shared__ unsigned short tile[32][33];
    const int bx = blockIdx.x * 32;  // col base
    const int by = blockIdx.y * 32;  // row base
    const int x = threadIdx.x;
    for (int y = threadIdx.y; y < 32; y += 8)
        tile[y][x] = f2h(in[(long long)(by + y) * C + (bx + x)]);
    __syncthreads();
    for (int y = threadIdx.y; y < 32; y += 8)
        out[(long long)(bx + y) * C + (by + x)] = tile[x][y];
}

// fp16 transpose, batched via z
__global__ __launch_bounds__(256) void transpose_f16(
    const unsigned short* __restrict__ in,
    unsigned short* __restrict__ out,
    int rows, int cols,
    long long sIn, long long sOut)
{
    __shared__ unsigned short tile[32][33];
    const unsigned short* ip = in  + (long long)blockIdx.z * sIn;
    unsigned short*       op = out + (long long)blockIdx.z * sOut;
    const int bx = blockIdx.x * 32;
    const int by = blockIdx.y * 32;
    const int x = threadIdx.x;
    for (int y = threadIdx.y; y < 32; y += 8)
        tile[y][x] = ip[(long long)(by + y) * cols + (bx + x)];
    __syncthreads();
    for (int y = threadIdx.y; y < 32; y += 8)
        op[(long long)(bx + y) * rows + (by + x)] = tile[x][y];
}

// one 256-thread block per row of 1024; fp16 in, fp32 params, fp32 out
__global__ __launch_bounds__(256) void layernorm_h(
    const unsigned short* __restrict__ X,
    const float* __restrict__ W,
    const float* __restrict__ Bv,
    float* __restrict__ Y)
{
    const int row = blockIdx.x;
    const int tid = threadIdx.x;
    ushort4 u = ((const ushort4*)(X + (long long)row * 1024))[tid];
    float f0 = h2f(u.x), f1 = h2f(u.y), f2 = h2f(u.z), f3 = h2f(u.w);
    float s  = f0 + f1 + f2 + f3;
    float ss = f0 * f0 + f1 * f1 + f2 * f2 + f3 * f3;
    #pragma unroll
    for (int off = 32; off > 0; off >>= 1) {
        s  += __shfl_down(s, off);
        ss += __shfl_down(ss, off);
    }
    __shared__ float red[2][4];
    const int wv = tid >> 6;
    if ((tid & 63) == 0) { red[0][wv] = s; red[1][wv] = ss; }
    __syncthreads();
    float S  = red[0][0] + red[0][1] + red[0][2] + red[0][3];
    float SS = red[1][0] + red[1][1] + red[1][2] + red[1][3];
    float mu  = S * (1.f / 1024.f);
    float var = SS * (1.f / 1024.f) - mu * mu;
    float rs  = rsqrtf(var + 1e-5f);
    float4 w4 = ((const float4*)W)[tid];
    float4 b4 = ((const float4*)Bv)[tid];
    float4 o;
    o.x = (f0 - mu) * rs * w4.x + b4.x;
    o.y = (f1 - mu) * rs * w4.y + b4.y;
    o.z = (f2 - mu) * rs * w4.z + b4.z;
    o.w = (f3 - mu) * rs * w4.w + b4.w;
    ((float4*)(Y + (long long)row * 1024))[tid] = o;
}

extern "C" void kernel_launch(void* const* d_in, const int* in_sizes, int n_in,
                              void* d_out, int out_size, void* d_ws, size_t ws_size,
                              hipStream_t stream)
{
    const int C  = 1024;
    const int T  = 2048;
    const int NB = 8;
    const int MT = NB * T;  // 16384 rows

    const float* x = (const float*)d_in[0];
    const float* W1q = (const float*)d_in[1];
    const float* b1q = (const float*)d_in[2];
    const float* W2q = (const float*)d_in[3];
    const float* b2q = (const float*)d_in[4];
    const float* W1k = (const float*)d_in[5];
    const float* b1k = (const float*)d_in[6];
    const float* W2k = (const float*)d_in[7];
    const float* b2k = (const float*)d_in[8];
    const float* W1v = (const float*)d_in[9];
    const float* b1v = (const float*)d_in[10];
    const float* W2v = (const float*)d_in[11];
    const float* b2v = (const float*)d_in[12];
    const float* lnw = (const float*)d_in[13];
    const float* lnb = (const float*)d_in[14];

    char* wsp = (char*)d_ws;
    auto take = [&](size_t bytes) {
        char* p = wsp;
        wsp += (bytes + 255) & ~(size_t)255;
        return p;
    };

    const size_t MATE = (size_t)MT * C;  // elements per [16384][1024] matrix

    unsigned short* W1T  = (unsigned short*)take((size_t)3 * C * C * 2);
    unsigned short* W2T  = (unsigned short*)take((size_t)3 * C * C * 2);
    unsigned short* xb   = (unsigned short*)take(MATE * 2);
    unsigned short* qkv  = (unsigned short*)take(3 * MATE * 2);  // q,k,v contiguous
    unsigned short* hreg = (unsigned short*)take(3 * MATE * 2);  // h; later scb+opre
    unsigned short* qb   = qkv;
    unsigned short* kb   = qkv + MATE;
    unsigned short* vb   = qkv + 2 * MATE;
    unsigned short* vT   = xb;                               // xb dead after MLP1
    unsigned short* scb  = hreg;                             // 8*T*T = 2*MATE elems
    unsigned short* opre = hreg + (size_t)NB * T * T;        // MATE elems — exact fit

    // x: fp32 -> fp16
    cvt_f32_f16<<<dim3(MT * C / 1024, 1, 1), dim3(256, 1, 1), 0, stream>>>(
        (const float4*)x, (ushort4*)xb);

    // all weights: fp32 -> fp16 transposed, one dispatch
    wprep<<<dim3(C / 32, C / 32, 6), dim3(32, 8, 1), 0, stream>>>(
        W1q, W1k, W1v, W2q, W2k, W2v, W1T, W2T);

    dim3 blk(256, 1, 1);

    // MLP GEMM1 (z = head): h_z = GELU(x @ W1_z + b1_z)
    gemm_bt<OP_BIAS_GELU, false><<<dim3(C / BN, MT / BM, 3), blk, 0, stream>>>(
        xb, W1T, hreg, b1q, b1k, b1v, MT, C, C,
        0, (long long)C * C, (long long)MATE, 1.f);

    // MLP GEMM2 (z = head): {q,k,v}_z = h_z @ W2_z + b2_z
    gemm_bt<OP_BIAS, false><<<dim3(C / BN, MT / BM, 3), blk, 0, stream>>>(
        hreg, W2T, qkv, b2q, b2k, b2v, MT, C, C,
        (long long)MATE, (long long)C * C, (long long)MATE, 1.f);

    // vT[b] = v[b]^T ([C][T] per batch) for the scores@v GEMM's BT operand
    transpose_f16<<<dim3(C / 32, T / 32, NB), dim3(32, 8, 1), 0, stream>>>(
        vb, vT, T, C, (long long)T * C, (long long)T * C);

    // scores = tril(q @ k^T) / sqrt(C*T); above-diagonal tiles skipped
    float inv_scale = 1.0f / sqrtf((float)C * (float)T);
    gemm_bt<OP_SCALE_MASK, false><<<dim3(T / BN, T / BM, NB), blk, 0, stream>>>(
        qb, kb, scb, nullptr, nullptr, nullptr, T, T, C,
        (long long)T * C, (long long)T * C, (long long)T * T, inv_scale);

    // out_pre = scores @ v (K limited to bm+BM by causality)
    gemm_bt<OP_NONE, true><<<dim3(C / BN, T / BM, NB), blk, 0, stream>>>(
        scb, vT, opre, nullptr, nullptr, nullptr, T, C, T,
        (long long)T * T, (long long)T * C, (long long)T * C, 1.f);

    layernorm_h<<<dim3(MT, 1, 1), dim3(256, 1, 1), 0, stream>>>(
        opre, lnw, lnb, (float*)d_out);
}

// Round 5
// 616.533 us; speedup vs baseline: 1.3503x; 1.0836x over previous
//
#include <hip/hip_runtime.h>
#include <math.h>

#define BM 128
#define BN 128
#define BK 64

typedef _Float16 f16x8 __attribute__((ext_vector_type(8)));
typedef __attribute__((ext_vector_type(4))) float f32x4;

typedef const __attribute__((address_space(1))) void* gas_ptr;
typedef __attribute__((address_space(3))) void* las_ptr;

enum { OP_NONE = 0, OP_BIAS_GELU = 1, OP_BIAS = 2, OP_SCALE_MASK = 3 };

__device__ __forceinline__ unsigned short f2h(float f) {
    _Float16 h = (_Float16)f;  // RTNE
    unsigned short u;
    __builtin_memcpy(&u, &h, 2);
    return u;
}
__device__ __forceinline__ float h2f(unsigned short u) {
    _Float16 h;
    __builtin_memcpy(&h, &u, 2);
    return (float)h;
}

// C = A @ B, B given transposed (BT is [N][K] row-major). A [M][K], C [M][N].
// fp16 in/out, fp32 accumulate. BK=64 with XOR-swizzled LDS staging (0 bank
// conflicts, verified R4). GRID IS (M-tiles, N-tiles, z): m = blockIdx.x so
// the n-blocks sharing an A-stripe have linear ids m + Mtiles*(n + Ntiles*z)
// with Mtiles % 8 == 0 -> same XCD -> A-stripe fetched once per XCD L2
// instead of once per XCD *per n-block* (R4: 400 MB over-fetch).
template <int EPI, bool CAUSAL_K>
__global__ __launch_bounds__(256) void gemm_bt(
    const unsigned short* __restrict__ A,
    const unsigned short* __restrict__ BT,
    unsigned short* __restrict__ Cw,
    const float* __restrict__ bias0,
    const float* __restrict__ bias1,
    const float* __restrict__ bias2,
    int M, int N, int K,
    long long sA, long long sB, long long sC,
    float scale)
{
    __shared__ __align__(16) unsigned short As[BM * BK];
    __shared__ __align__(16) unsigned short Bs[BN * BK];

    const int tid  = threadIdx.x;
    const int wave = tid >> 6;
    const int lane = tid & 63;

    const int bm = blockIdx.x * BM;   // M fastest -> XCD-local A reuse
    const int bn = blockIdx.y * BN;
    const int z  = blockIdx.z;

    // scores tiles fully above the diagonal are never read downstream
    if (EPI == OP_SCALE_MASK && bn >= bm + BM) return;

    const unsigned short* Ab = A  + (long long)z * sA;
    const unsigned short* Bb = BT + (long long)z * sB;
    unsigned short*       Cb = Cw + (long long)z * sC;
    const float* bias = nullptr;
    if (EPI == OP_BIAS || EPI == OP_BIAS_GELU)
        bias = (z == 0) ? bias0 : (z == 1) ? bias1 : bias2;

    const int wm = (wave >> 1) * 64;  // wave's 64x64 quadrant
    const int wn = (wave & 1) * 64;

    f32x4 acc[4][4];
    #pragma unroll
    for (int i = 0; i < 4; i++)
        #pragma unroll
        for (int j = 0; j < 4; j++)
            acc[i][j] = (f32x4){0.f, 0.f, 0.f, 0.f};

    int Keff = K;
    if (CAUSAL_K) {
        int kl = bm + BM;
        Keff = kl < K ? kl : K;
    }

    const int srow = lane >> 3;                          // row within 8-row slab
    const int gchw = ((lane & 7) ^ (srow & 7)) * 8;      // swizzled chunk, halfwords
    const int fr   = lane & 15;
    const int quad = lane >> 4;

    for (int k0 = 0; k0 < Keff; k0 += BK) {
        #pragma unroll
        for (int s = 0; s < 4; ++s) {
            const int t   = wave * 4 + s;
            const int row = t * 8 + srow;
            const unsigned short* gA = Ab + (long long)(bm + row) * K + (k0 + gchw);
            __builtin_amdgcn_global_load_lds((gas_ptr)(const void*)gA,
                                             (las_ptr)(void*)&As[t * 512 + lane * 8],
                                             16, 0, 0);
            const unsigned short* gB = Bb + (long long)(bn + row) * K + (k0 + gchw);
            __builtin_amdgcn_global_load_lds((gas_ptr)(const void*)gB,
                                             (las_ptr)(void*)&Bs[t * 512 + lane * 8],
                                             16, 0, 0);
        }
        __syncthreads();  // drains vmcnt -> staged data visible

        #pragma unroll
        for (int kk = 0; kk < 2; ++kk) {
            f16x8 fa[4], fb[4];
            #pragma unroll
            for (int i = 0; i < 4; i++) {
                const int row  = wm + i * 16 + fr;
                const int slot = row * 8 + ((kk * 4 + quad) ^ (fr & 7));
                fa[i] = *(const f16x8*)&As[slot * 8];
            }
            #pragma unroll
            for (int j = 0; j < 4; j++) {
                const int row  = wn + j * 16 + fr;
                const int slot = row * 8 + ((kk * 4 + quad) ^ (fr & 7));
                fb[j] = *(const f16x8*)&Bs[slot * 8];
            }
            #pragma unroll
            for (int i = 0; i < 4; i++)
                #pragma unroll
                for (int j = 0; j < 4; j++)
                    acc[i][j] = __builtin_amdgcn_mfma_f32_16x16x32_f16(
                        fa[i], fb[j], acc[i][j], 0, 0, 0);
        }
        __syncthreads();  // protect LDS before next stage overwrites
    }

    // epilogue: C/D layout col=lane&15, row=(lane>>4)*4+reg  [m89/m91]
    const int er = quad;
    const int ec = fr;
    #pragma unroll
    for (int j = 0; j < 4; j++) {
        const int col = bn + wn + j * 16 + ec;
        float bj = 0.f;
        if (EPI == OP_BIAS || EPI == OP_BIAS_GELU) bj = bias[col];
        #pragma unroll
        for (int i = 0; i < 4; i++) {
            #pragma unroll
            for (int r = 0; r < 4; r++) {
                const int row = bm + wm + i * 16 + er * 4 + r;
                float v = acc[i][j][r];
                if (EPI == OP_BIAS_GELU) {
                    v += bj;
                    v = 0.5f * v * (1.f + erff(v * 0.70710678118654752f));
                } else if (EPI == OP_BIAS) {
                    v += bj;
                } else if (EPI == OP_SCALE_MASK) {
                    v *= scale;
                    if (col > row) v = 0.f;
                }
                Cb[(long long)row * N + col] = f2h(v);
            }
        }
    }
}

// fp32 -> fp16 elementwise (n divisible by 1024)
__global__ __launch_bounds__(256) void cvt_f32_f16(
    const float4* __restrict__ in, ushort4* __restrict__ out)
{
    int i = blockIdx.x * 256 + threadIdx.x;
    float4 f = in[i];
    ushort4 o;
    o.x = f2h(f.x); o.y = f2h(f.y); o.z = f2h(f.z); o.w = f2h(f.w);
    out[i] = o;
}

// all six weight matrices: fp32 -> fp16 transposed, one dispatch (z=0..5).
__global__ __launch_bounds__(256) void wprep(
    const float* __restrict__ s0, const float* __restrict__ s1,
    const float* __restrict__ s2, const float* __restrict__ s3,
    const float* __restrict__ s4, const float* __restrict__ s5,
    unsigned short* __restrict__ W1T, unsigned short* __restrict__ W2T)
{
    const int C = 1024;
    const int z = blockIdx.z;
    const float* in = (z == 0) ? s0 : (z == 1) ? s1 : (z == 2) ? s2
                    : (z == 3) ? s3 : (z == 4) ? s4 : s5;
    unsigned short* out = (z < 3) ? (W1T + (long long)z * C * C)
                                  : (W2T + (long long)(z - 3) * C * C);
    __shared__ unsigned short tile[32][33];
    const int bx = blockIdx.x * 32;  // col base
    const int by = blockIdx.y * 32;  // row base
    const int x = threadIdx.x;
    for (int y = threadIdx.y; y < 32; y += 8)
        tile[y][x] = f2h(in[(long long)(by + y) * C + (bx + x)]);
    __syncthreads();
    for (int y = threadIdx.y; y < 32; y += 8)
        out[(long long)(bx + y) * C + (by + x)] = tile[x][y];
}

// fp16 transpose, batched via z
__global__ __launch_bounds__(256) void transpose_f16(
    const unsigned short* __restrict__ in,
    unsigned short* __restrict__ out,
    int rows, int cols,
    long long sIn, long long sOut)
{
    __shared__ unsigned short tile[32][33];
    const unsigned short* ip = in  + (long long)blockIdx.z * sIn;
    unsigned short*       op = out + (long long)blockIdx.z * sOut;
    const int bx = blockIdx.x * 32;
    const int by = blockIdx.y * 32;
    const int x = threadIdx.x;
    for (int y = threadIdx.y; y < 32; y += 8)
        tile[y][x] = ip[(long long)(by + y) * cols + (bx + x)];
    __syncthreads();
    for (int y = threadIdx.y; y < 32; y += 8)
        op[(long long)(bx + y) * rows + (by + x)] = tile[x][y];
}

// one 256-thread block per row of 1024; fp16 in, fp32 params, fp32 out
__global__ __launch_bounds__(256) void layernorm_h(
    const unsigned short* __restrict__ X,
    const float* __restrict__ W,
    const float* __restrict__ Bv,
    float* __restrict__ Y)
{
    const int row = blockIdx.x;
    const int tid = threadIdx.x;
    ushort4 u = ((const ushort4*)(X + (long long)row * 1024))[tid];
    float f0 = h2f(u.x), f1 = h2f(u.y), f2 = h2f(u.z), f3 = h2f(u.w);
    float s  = f0 + f1 + f2 + f3;
    float ss = f0 * f0 + f1 * f1 + f2 * f2 + f3 * f3;
    #pragma unroll
    for (int off = 32; off > 0; off >>= 1) {
        s  += __shfl_down(s, off);
        ss += __shfl_down(ss, off);
    }
    __shared__ float red[2][4];
    const int wv = tid >> 6;
    if ((tid & 63) == 0) { red[0][wv] = s; red[1][wv] = ss; }
    __syncthreads();
    float S  = red[0][0] + red[0][1] + red[0][2] + red[0][3];
    float SS = red[1][0] + red[1][1] + red[1][2] + red[1][3];
    float mu  = S * (1.f / 1024.f);
    float var = SS * (1.f / 1024.f) - mu * mu;
    float rs  = rsqrtf(var + 1e-5f);
    float4 w4 = ((const float4*)W)[tid];
    float4 b4 = ((const float4*)Bv)[tid];
    float4 o;
    o.x = (f0 - mu) * rs * w4.x + b4.x;
    o.y = (f1 - mu) * rs * w4.y + b4.y;
    o.z = (f2 - mu) * rs * w4.z + b4.z;
    o.w = (f3 - mu) * rs * w4.w + b4.w;
    ((float4*)(Y + (long long)row * 1024))[tid] = o;
}

extern "C" void kernel_launch(void* const* d_in, const int* in_sizes, int n_in,
                              void* d_out, int out_size, void* d_ws, size_t ws_size,
                              hipStream_t stream)
{
    const int C  = 1024;
    const int T  = 2048;
    const int NB = 8;
    const int MT = NB * T;  // 16384 rows

    const float* x = (const float*)d_in[0];
    const float* W1q = (const float*)d_in[1];
    const float* b1q = (const float*)d_in[2];
    const float* W2q = (const float*)d_in[3];
    const float* b2q = (const float*)d_in[4];
    const float* W1k = (const float*)d_in[5];
    const float* b1k = (const float*)d_in[6];
    const float* W2k = (const float*)d_in[7];
    const float* b2k = (const float*)d_in[8];
    const float* W1v = (const float*)d_in[9];
    const float* b1v = (const float*)d_in[10];
    const float* W2v = (const float*)d_in[11];
    const float* b2v = (const float*)d_in[12];
    const float* lnw = (const float*)d_in[13];
    const float* lnb = (const float*)d_in[14];

    char* wsp = (char*)d_ws;
    auto take = [&](size_t bytes) {
        char* p = wsp;
        wsp += (bytes + 255) & ~(size_t)255;
        return p;
    };

    const size_t MATE = (size_t)MT * C;  // elements per [16384][1024] matrix

    unsigned short* W1T  = (unsigned short*)take((size_t)3 * C * C * 2);
    unsigned short* W2T  = (unsigned short*)take((size_t)3 * C * C * 2);
    unsigned short* xb   = (unsigned short*)take(MATE * 2);
    unsigned short* qkv  = (unsigned short*)take(3 * MATE * 2);  // q,k,v contiguous
    unsigned short* hreg = (unsigned short*)take(3 * MATE * 2);  // h; later scb+opre
    unsigned short* qb   = qkv;
    unsigned short* kb   = qkv + MATE;
    unsigned short* vb   = qkv + 2 * MATE;
    unsigned short* vT   = xb;                               // xb dead after MLP1
    unsigned short* scb  = hreg;                             // 8*T*T = 2*MATE elems
    unsigned short* opre = hreg + (size_t)NB * T * T;        // MATE elems — exact fit

    // x: fp32 -> fp16
    cvt_f32_f16<<<dim3(MT * C / 1024, 1, 1), dim3(256, 1, 1), 0, stream>>>(
        (const float4*)x, (ushort4*)xb);

    // all weights: fp32 -> fp16 transposed, one dispatch
    wprep<<<dim3(C / 32, C / 32, 6), dim3(32, 8, 1), 0, stream>>>(
        W1q, W1k, W1v, W2q, W2k, W2v, W1T, W2T);

    dim3 blk(256, 1, 1);

    // MLP GEMM1 (z = head): h_z = GELU(x @ W1_z + b1_z)   grid (M,N,z)
    gemm_bt<OP_BIAS_GELU, false><<<dim3(MT / BM, C / BN, 3), blk, 0, stream>>>(
        xb, W1T, hreg, b1q, b1k, b1v, MT, C, C,
        0, (long long)C * C, (long long)MATE, 1.f);

    // MLP GEMM2 (z = head): {q,k,v}_z = h_z @ W2_z + b2_z
    gemm_bt<OP_BIAS, false><<<dim3(MT / BM, C / BN, 3), blk, 0, stream>>>(
        hreg, W2T, qkv, b2q, b2k, b2v, MT, C, C,
        (long long)MATE, (long long)C * C, (long long)MATE, 1.f);

    // vT[b] = v[b]^T ([C][T] per batch) for the scores@v GEMM's BT operand
    transpose_f16<<<dim3(C / 32, T / 32, NB), dim3(32, 8, 1), 0, stream>>>(
        vb, vT, T, C, (long long)T * C, (long long)T * C);

    // scores = tril(q @ k^T) / sqrt(C*T); above-diagonal tiles skipped
    float inv_scale = 1.0f / sqrtf((float)C * (float)T);
    gemm_bt<OP_SCALE_MASK, false><<<dim3(T / BM, T / BN, NB), blk, 0, stream>>>(
        qb, kb, scb, nullptr, nullptr, nullptr, T, T, C,
        (long long)T * C, (long long)T * C, (long long)T * T, inv_scale);

    // out_pre = scores @ v (K limited to bm+BM by causality)
    gemm_bt<OP_NONE, true><<<dim3(T / BM, C / BN, NB), blk, 0, stream>>>(
        scb, vT, opre, nullptr, nullptr, nullptr, T, C, T,
        (long long)T * T, (long long)T * C, (long long)T * C, 1.f);

    layernorm_h<<<dim3(MT, 1, 1), dim3(256, 1, 1), 0, stream>>>(
        opre, lnw, lnb, (float*)d_out);
}